// Round 3
// baseline (662.893 us; speedup 1.0000x reference)
//
#include <hip/hip_runtime.h>
#include <hip/hip_fp16.h>
#include <cstddef>

static constexpr int BTOT = 131072;     // B*T
static constexpr int RESO_ = 128;
static constexpr int R2_ = RESO_ * RESO_;   // 16384
static constexpr int NBIN = 4 * R2_;        // B*R2 = 65536
static constexpr int HDIM = 128;
static constexpr int CDIM = 64;

typedef __attribute__((ext_vector_type(8))) short short8;
typedef _Float16 half8 __attribute__((ext_vector_type(8)));
typedef _Float16 half2v __attribute__((ext_vector_type(2)));
typedef __attribute__((ext_vector_type(4))) float floatx4;

__device__ __forceinline__ unsigned short f2h(float f) {
  return __half_as_ushort(__float2half(f));   // RTN
}
__device__ __forceinline__ float h2f(unsigned short h) {
  return __half2float(__ushort_as_half(h));
}
// relu on packed f16: sign bit = bit15, so int16 compare works (+0.0 = 0x0000)
__device__ __forceinline__ short8 relu8(short8 v) {
#pragma unroll
  for (int i = 0; i < 8; ++i) v[i] = (v[i] < (short)0) ? (short)0 : v[i];
  return v;
}

// ---------- bin indices for the 3 planes (+ fused count) ----------
__global__ __launch_bounds__(256) void k_idxcount(const float* __restrict__ p,
                                                  int* __restrict__ idx,
                                                  int* __restrict__ cnt) {
  int pt = blockIdx.x * 256 + threadIdx.x;
  const float DIVC = (float)(1.0 + 0.1 + 1e-5);
  const float HI = (float)(1.0 - 1e-5);
  float x = p[pt * 3 + 0], y = p[pt * 3 + 1], z = p[pt * 3 + 2];
  float nx = fminf(fmaxf(x / DIVC + 0.5f, 0.0f), HI);
  float ny = fminf(fmaxf(y / DIVC + 0.5f, 0.0f), HI);
  float nz = fminf(fmaxf(z / DIVC + 0.5f, 0.0f), HI);
  int ix = (int)(nx * (float)RESO_);
  int iy = (int)(ny * (float)RESO_);
  int iz = (int)(nz * (float)RESO_);
  int off = (pt >> 15) * R2_;
  int i0 = ix + RESO_ * iz + off;   // xz
  int i1 = ix + RESO_ * iy + off;   // xy
  int i2 = iy + RESO_ * iz + off;   // yz
  idx[0 * BTOT + pt] = i0;
  idx[1 * BTOT + pt] = i1;
  idx[2 * BTOT + pt] = i2;
  atomicAdd(&cnt[0 * NBIN + i0], 1);
  atomicAdd(&cnt[1 * NBIN + i1], 1);
  atomicAdd(&cnt[2 * NBIN + i2], 1);
}

__global__ __launch_bounds__(1024) void k_scan(const int* __restrict__ cnt,
                                               int* __restrict__ starts,
                                               int* __restrict__ cursor) {
  __shared__ int part[1024];
  int pl = blockIdx.x;
  int t = threadIdx.x;
  const int* c = cnt + pl * NBIN;
  int base = t * 64;
  int s = 0;
  for (int i = 0; i < 64; ++i) s += c[base + i];
  part[t] = s;
  __syncthreads();
  for (int off = 1; off < 1024; off <<= 1) {
    int v = (t >= off) ? part[t - off] : 0;
    __syncthreads();
    part[t] += v;
    __syncthreads();
  }
  int run = (t == 0) ? 0 : part[t - 1];
  int* st = starts + pl * (NBIN + 1);
  int* cur = cursor + pl * NBIN;
  for (int i = 0; i < 64; ++i) {
    st[base + i] = run;
    cur[base + i] = run;
    run += c[base + i];
  }
  if (t == 1023) st[NBIN] = run;
}

__global__ __launch_bounds__(256) void k_place(const int* __restrict__ idx,
                                               int* __restrict__ cursor,
                                               int* __restrict__ plist) {
  int e = blockIdx.x * 256 + threadIdx.x;    // 3*BTOT
  int pl = e / BTOT, pt = e - pl * BTOT;
  int pos = atomicAdd(&cursor[pl * NBIN + idx[e]], 1);
  plist[(size_t)pl * BTOT + pos] = pt;
}

// ---------- fc_pos -> f16 netA / poolB (8 cols/thread, 16B stores) ----------
__global__ __launch_bounds__(256) void k_fcpos(const float* __restrict__ p,
                                               const float* __restrict__ w,
                                               const float* __restrict__ b,
                                               unsigned short* __restrict__ netA,
                                               unsigned short* __restrict__ poolB) {
  int t = blockIdx.x * 256 + threadIdx.x;     // BTOT*32 threads
  int pt = t >> 5;
  int g = (t & 31) * 8;                       // col group of 8
  float x0 = p[pt * 3 + 0], x1 = p[pt * 3 + 1], x2 = p[pt * 3 + 2];
  short8 o;
#pragma unroll
  for (int j = 0; j < 8; ++j) {
    int col = g + j;
    float v = b[col] + x0 * w[col] + x1 * w[256 + col] + x2 * w[512 + col];
    o[j] = (short)f2h(v);
  }
  if (g < 128) *(short8*)(netA + (size_t)pt * HDIM + g) = o;
  else         *(short8*)(poolB + (size_t)pt * HDIM + (g - 128)) = o;
}

// ---------- weight packing into MFMA B-fragment order (single f16) ----------
__global__ __launch_bounds__(256) void k_pack(const float* __restrict__ bw0,
                                              const float* __restrict__ bw1,
                                              const float* __restrict__ bws,
                                              unsigned short* __restrict__ P1,
                                              unsigned short* __restrict__ P2) {
  int t = blockIdx.x * 256 + threadIdx.x;
  if (t >= 5 * 20 * 8 * 64) return;
  int lane = t & 63;
  int r = t >> 6;
  int nt = r & 7; r >>= 3;
  int kb20 = r % 20;
  int l = r / 20;
  int quad = lane >> 4;
  int n = nt * 16 + (lane & 15);
#pragma unroll
  for (int j = 0; j < 8; ++j) {
    if (kb20 < 8) {
      int k = kb20 * 32 + quad * 8 + j;
      float v = bw0[((size_t)l * 256 + k) * 128 + n];
      size_t didx = (((size_t)(l * 8 + kb20) * 8 + nt) * 64 + lane) * 8 + j;
      P1[didx] = f2h(v);
    } else {
      int kb = kb20 - 8;
      int k = kb * 32 + quad * 8 + j;
      float v = (k < 256) ? bws[((size_t)l * 256 + k) * 128 + n]
                          : bw1[((size_t)l * 128 + (k - 256)) * 128 + n];
      size_t didx = (((size_t)(l * 12 + kb) * 8 + nt) * 64 + lane) * 8 + j;
      P2[didx] = f2h(v);
    }
  }
}

// ---------- fc_c weight packing: P3[(kb*4+nt)*64+lane][j] ----------
__global__ __launch_bounds__(256) void k_packc(const float* __restrict__ fccw,
                                               unsigned short* __restrict__ P3) {
  int t = blockIdx.x * 256 + threadIdx.x;    // 16 frags x 64 lanes
  if (t >= 16 * 64) return;
  int lane = t & 63;
  int fr = t >> 6;
  int nt = fr & 3, kb = fr >> 2;
  int quad = lane >> 4;
  int n = nt * 16 + (lane & 15);
#pragma unroll
  for (int j = 0; j < 8; ++j) {
    int k = kb * 32 + quad * 8 + j;
    P3[((size_t)fr * 64 + lane) * 8 + j] = f2h(fccw[(size_t)k * 64 + n]);
  }
}

// ---------- list-based pooling max (packed f16 max), 4 bins/wave ----------
// grid (NBIN/16, 3); block 256 = 4 waves x 4 bins. Lane covers 2 channels.
__global__ __launch_bounds__(256) void k_poolmax(const unsigned short* __restrict__ net,
                                                 const int* __restrict__ starts,
                                                 const int* __restrict__ plist,
                                                 unsigned short* __restrict__ seg) {
  int tid = threadIdx.x;
  int pl = blockIdx.y;
  int wv = tid >> 6, lane = tid & 63;
  int bin0 = blockIdx.x * 16 + wv * 4;
  const int* st = starts + pl * (NBIN + 1) + bin0;
  int sa[5];
#pragma unroll
  for (int i = 0; i < 5; ++i) sa[i] = st[i];
  const int* pli = plist + (size_t)pl * BTOT;
  half2v v[4];
#pragma unroll
  for (int i = 0; i < 4; ++i) {
    v[i][0] = (_Float16)(-65504.0f);
    v[i][1] = (_Float16)(-65504.0f);
  }
  int lmax = 0;
#pragma unroll
  for (int i = 0; i < 4; ++i) lmax = max(lmax, sa[i + 1] - sa[i]);
  for (int k = 0; k < lmax; ++k) {
#pragma unroll
    for (int i = 0; i < 4; ++i) {         // 4 independent load chains in flight
      int t = sa[i] + k;
      int kk = max(min(t, sa[i + 1] - 1), 0);
      int pid = pli[kk];
      unsigned u = *(const unsigned*)(net + (size_t)pid * 128 + lane * 2);
      half2v h = *(half2v*)&u;
      if (t < sa[i + 1]) v[i] = __builtin_elementwise_max(v[i], h);  // v_pk_max_f16
    }
  }
#pragma unroll
  for (int i = 0; i < 4; ++i) {
    if (sa[i + 1] > sa[i]) {               // empty bins never gathered
      *(unsigned*)(seg + ((size_t)pl * NBIN + bin0 + i) * 128 + lane * 2) =
          *(unsigned*)&v[i];
    }
  }
}

// ---------- fused resblock with in-kernel 3-plane gather (all f16) ----------
// 64 rows/block, 4 waves = col quarters; each wave 64 rows x 32 cols
// (acc[4][2]): 8 MFMAs per 2 weight-fragment loads. Measured trend:
// 16r=71us, 32r=51us -> weight reuse per wave is the lever, occupancy is not
// (mode0==mode1 timing shows gather latency isn't the limiter).
// LDS 51.2KB -> 3 blocks/CU.
// If cOut != nullptr: additionally computes c = net @ fc_c + bc (fused fc_c).
__global__ __launch_bounds__(256, 3) void k_resblock(
    unsigned short* __restrict__ netA, const unsigned short* __restrict__ segB,
    const int* __restrict__ idx, int mode,
    const unsigned short* __restrict__ P1, const unsigned short* __restrict__ P2,
    const float* __restrict__ b0, const float* __restrict__ b1,
    const unsigned short* __restrict__ P3, const float* __restrict__ bc,
    unsigned short* __restrict__ cOut) {
  __shared__ __align__(16) unsigned short xh[64][264];
  __shared__ __align__(16) unsigned short th[64][136];
  int tid = threadIdx.x;
  int rows0 = blockIdx.x * 64;

  // stage A: x = [netA | pooled] f16, 8-col groups
#pragma unroll
  for (int i = 0; i < 8; ++i) {
    int g8 = i * 256 + tid;             // [0,2048): 64 rows x 32 groups
    int row = g8 >> 5;
    int col = (g8 & 31) * 8;
    int grow = rows0 + row;
    if (col < 128) {
      *(short8*)&xh[row][col] = *(const short8*)(netA + (size_t)grow * 128 + col);
    } else {
      int cc = col - 128;
      if (mode == 0) {
        *(short8*)&xh[row][col] = *(const short8*)(segB + (size_t)grow * 128 + cc);
      } else {
        int i0 = idx[grow], i1 = idx[BTOT + grow], i2 = idx[2 * BTOT + grow];
        short8 a = *(const short8*)(segB + (size_t)i0 * 128 + cc);
        short8 b8 = *(const short8*)(segB + (size_t)NBIN * 128 + (size_t)i1 * 128 + cc);
        short8 c8 = *(const short8*)(segB + (size_t)2 * NBIN * 128 + (size_t)i2 * 128 + cc);
        half8 s = *(half8*)&a + *(half8*)&b8 + *(half8*)&c8;   // v_pk_add_f16 x8
        *(short8*)&xh[row][col] = *(short8*)&s;
      }
    }
  }
  __syncthreads();

  int lane = tid & 63;
  int cg = tid >> 6;               // col quarter [0,4)
  int quad = lane >> 4;
  int m0 = lane & 15;

  // ---- stage 1: t = relu(x) @ w0 + b0 ----
  floatx4 acc[4][2] = {};
  for (int kb = 0; kb < 8; ++kb) {
    half8 a[4];
#pragma unroll
    for (int rs = 0; rs < 4; ++rs) {
      short8 as = relu8(*(const short8*)&xh[m0 + rs * 16][kb * 32 + quad * 8]);
      a[rs] = *(half8*)&as;
    }
    const short8* wf = (const short8*)P1 + ((size_t)(kb * 8 + cg * 2) * 64 + lane);
#pragma unroll
    for (int nti = 0; nti < 2; ++nti) {
      short8 bs = wf[nti * 64];
      half8 bw = *(half8*)&bs;
#pragma unroll
      for (int rs = 0; rs < 4; ++rs)
        acc[rs][nti] = __builtin_amdgcn_mfma_f32_16x16x32_f16(a[rs], bw, acc[rs][nti], 0, 0, 0);
    }
  }
  // epilogue 1: bias + relu -> th (f16)
#pragma unroll
  for (int rs = 0; rs < 4; ++rs) {
#pragma unroll
    for (int nti = 0; nti < 2; ++nti) {
      int col = cg * 32 + nti * 16 + m0;
      float bb = b0[col];
#pragma unroll
      for (int r = 0; r < 4; ++r) {
        int row = rs * 16 + quad * 4 + r;
        th[row][col] = f2h(fmaxf(acc[rs][nti][r] + bb, 0.0f));
      }
    }
  }
  __syncthreads();

  // ---- stage 2: out = x @ ws + relu_t @ w1 + b1 ----
  floatx4 acc2[4][2] = {};
  for (int kb = 0; kb < 12; ++kb) {
    half8 a[4];
#pragma unroll
    for (int rs = 0; rs < 4; ++rs) {
      short8 as;
      if (kb < 8) as = *(const short8*)&xh[m0 + rs * 16][kb * 32 + quad * 8];
      else        as = *(const short8*)&th[m0 + rs * 16][(kb - 8) * 32 + quad * 8];
      a[rs] = *(half8*)&as;
    }
    const short8* wf = (const short8*)P2 + ((size_t)(kb * 8 + cg * 2) * 64 + lane);
#pragma unroll
    for (int nti = 0; nti < 2; ++nti) {
      short8 bs = wf[nti * 64];
      half8 bw = *(half8*)&bs;
#pragma unroll
      for (int rs = 0; rs < 4; ++rs)
        acc2[rs][nti] = __builtin_amdgcn_mfma_f32_16x16x32_f16(a[rs], bw, acc2[rs][nti], 0, 0, 0);
    }
  }

  if (!cOut) {
    // epilogue 2: bias + f16 store (in-place; block owns rows)
#pragma unroll
    for (int rs = 0; rs < 4; ++rs) {
#pragma unroll
      for (int nti = 0; nti < 2; ++nti) {
        int col = cg * 32 + nti * 16 + m0;
        float bb = b1[col];
#pragma unroll
        for (int r = 0; r < 4; ++r) {
          int row = rows0 + rs * 16 + quad * 4 + r;
          netA[(size_t)row * 128 + col] = f2h(acc2[rs][nti][r] + bb);
        }
      }
    }
  } else {
    // fused fc_c: round-trip net through xh, then MFMAs per wave
    __syncthreads();                     // all waves done reading xh/th
#pragma unroll
    for (int rs = 0; rs < 4; ++rs) {
#pragma unroll
      for (int nti = 0; nti < 2; ++nti) {
        int col = cg * 32 + nti * 16 + m0;
        float bb = b1[col];
#pragma unroll
        for (int r = 0; r < 4; ++r) {
          int row = rs * 16 + quad * 4 + r;
          xh[row][col] = f2h(acc2[rs][nti][r] + bb);
        }
      }
    }
    __syncthreads();
    floatx4 acc3[4] = {};
    for (int kb = 0; kb < 4; ++kb) {
      short8 bs = *((const short8*)P3 + ((size_t)(kb * 4 + cg) * 64 + lane));
      half8 bw = *(half8*)&bs;
#pragma unroll
      for (int rs = 0; rs < 4; ++rs) {
        short8 as = *(const short8*)&xh[m0 + rs * 16][kb * 32 + quad * 8];
        acc3[rs] = __builtin_amdgcn_mfma_f32_16x16x32_f16(*(half8*)&as, bw, acc3[rs], 0, 0, 0);
      }
    }
    int col = cg * 16 + m0;
    float bb = bc[col];
#pragma unroll
    for (int rs = 0; rs < 4; ++rs) {
#pragma unroll
      for (int r = 0; r < 4; ++r) {
        int row = rows0 + rs * 16 + quad * 4 + r;
        cOut[(size_t)row * 64 + col] = f2h(acc3[rs][r] + bb);
      }
    }
  }
}

// ---------- fused list-based scatter-mean + transposed output ----------
// 4 bins per wave interleaved for load ILP.
__global__ __launch_bounds__(256) void k_meanout(const unsigned short* __restrict__ c,
                                                 const int* __restrict__ starts,
                                                 const int* __restrict__ plist,
                                                 float* __restrict__ out) {
  __shared__ float tile[64][65];
  int tid = threadIdx.x;
  int pb = blockIdx.y;                 // pl*4 + b
  int pl = pb >> 2;
  int b = pb & 3;
  int bin0 = blockIdx.x * 64;
  int w = tid >> 6, lane = tid & 63;
  const int* st = starts + pl * (NBIN + 1) + b * R2_ + bin0 + w * 16;
  const int* pli = plist + (size_t)pl * BTOT;
  for (int grp = 0; grp < 4; ++grp) {
    int sa[5];
#pragma unroll
    for (int i = 0; i < 5; ++i) sa[i] = st[grp * 4 + i];
    float sum[4] = {0.f, 0.f, 0.f, 0.f};
    int lmax = 0;
#pragma unroll
    for (int i = 0; i < 4; ++i) lmax = max(lmax, sa[i + 1] - sa[i]);
    for (int k = 0; k < lmax; ++k) {
#pragma unroll
      for (int i = 0; i < 4; ++i) {
        int t = sa[i] + k;
        int kk = max(min(t, sa[i + 1] - 1), 0);
        int pid = pli[kk];
        float v = h2f(c[(size_t)pid * 64 + lane]);
        if (t < sa[i + 1]) sum[i] += v;
      }
    }
#pragma unroll
    for (int i = 0; i < 4; ++i) {
      int lb = w * 16 + grp * 4 + i;
      tile[lb][lane] = sum[i] / fmaxf((float)(sa[i + 1] - sa[i]), 1.0f);
    }
  }
  __syncthreads();
#pragma unroll
  for (int i = 0; i < 16; ++i) {
    int e2 = i * 256 + tid;
    int ch = e2 >> 6, lb = e2 & 63;
    out[((size_t)pb * 64 + ch) * R2_ + bin0 + lb] = tile[lb][ch];
  }
}

extern "C" void kernel_launch(void* const* d_in, const int* in_sizes, int n_in,
                              void* d_out, int out_size, void* d_ws, size_t ws_size,
                              hipStream_t stream) {
  const float* p    = (const float*)d_in[0];
  const float* fcw  = (const float*)d_in[1];
  const float* fcb  = (const float*)d_in[2];
  const float* bw0  = (const float*)d_in[3];
  const float* bb0  = (const float*)d_in[4];
  const float* bw1  = (const float*)d_in[5];
  const float* bb1  = (const float*)d_in[6];
  const float* bws  = (const float*)d_in[7];
  const float* fccw = (const float*)d_in[8];
  const float* fccb = (const float*)d_in[9];
  float* out = (float*)d_out;

  char* ws = (char*)d_ws;
  const size_t P1_LAYER = 8 * 8 * 64 * 8;               // shorts
  const size_t P2_LAYER = 12 * 8 * 64 * 8;              // shorts

  size_t off = 0;
  unsigned short* netA = (unsigned short*)(ws + off); off += (size_t)BTOT * 128 * 2;
  unsigned short* cbuf = (unsigned short*)(ws + off); off += (size_t)BTOT * 64 * 2;
  int*   idx  = (int*)(ws + off);   off += (size_t)3 * BTOT * 4;
  unsigned short* P1 = (unsigned short*)(ws + off); off += 5 * P1_LAYER * 2;
  unsigned short* P2 = (unsigned short*)(ws + off); off += 5 * P2_LAYER * 2;
  unsigned short* P3 = (unsigned short*)(ws + off); off += (size_t)16 * 64 * 8 * 2;
  int* cntb   = (int*)(ws + off); off += (size_t)3 * NBIN * 4;
  int* starts = (int*)(ws + off); off += (size_t)3 * (NBIN + 1) * 4;
  int* cursor = (int*)(ws + off); off += (size_t)3 * NBIN * 4;
  int* plist  = (int*)(ws + off); off += (size_t)3 * BTOT * 4;
  off = (off + 255) & ~(size_t)255;
  unsigned short* seg = (unsigned short*)(ws + off); // 3*NBIN*128*2 = 50.3 MiB
  unsigned short* poolB = seg;       // fc_pos B-half; dead before first poolmax

  hipMemsetAsync(cntb, 0, (size_t)3 * NBIN * 4, stream);
  k_idxcount<<<BTOT / 256, 256, 0, stream>>>(p, idx, cntb);
  k_scan<<<3, 1024, 0, stream>>>(cntb, starts, cursor);
  k_place<<<3 * BTOT / 256, 256, 0, stream>>>(idx, cursor, plist);
  k_pack<<<200, 256, 0, stream>>>(bw0, bw1, bws, P1, P2);
  k_packc<<<4, 256, 0, stream>>>(fccw, P3);
  k_fcpos<<<BTOT * 32 / 256, 256, 0, stream>>>(p, fcw, fcb, netA, poolB);

  for (int blk = 0; blk < 5; ++blk) {
    if (blk > 0) {
      dim3 g(NBIN / 16, 3);
      k_poolmax<<<g, 256, 0, stream>>>(netA, starts, plist, seg);
    }
    k_resblock<<<BTOT / 64, 256, 0, stream>>>(
        netA, seg, idx, (blk > 0) ? 1 : 0,
        P1 + (size_t)blk * P1_LAYER, P2 + (size_t)blk * P2_LAYER,
        bb0 + (size_t)blk * 128, bb1 + (size_t)blk * 128,
        P3, fccb, (blk == 4) ? cbuf : (unsigned short*)nullptr);
  }

  dim3 gm(R2_ / 64, 12);
  k_meanout<<<gm, 256, 0, stream>>>(cbuf, starts, plist, out);
}

// Round 4
// 613.790 us; speedup vs baseline: 1.0800x; 1.0800x over previous
//
#include <hip/hip_runtime.h>
#include <hip/hip_fp16.h>
#include <cstddef>

static constexpr int BTOT = 131072;     // B*T
static constexpr int RESO_ = 128;
static constexpr int R2_ = RESO_ * RESO_;   // 16384
static constexpr int NBIN = 4 * R2_;        // B*R2 = 65536
static constexpr int HDIM = 128;
static constexpr int CDIM = 64;

typedef __attribute__((ext_vector_type(8))) short short8;
typedef _Float16 half8 __attribute__((ext_vector_type(8)));
typedef _Float16 half2v __attribute__((ext_vector_type(2)));
typedef __attribute__((ext_vector_type(4))) float floatx4;

__device__ __forceinline__ unsigned short f2h(float f) {
  return __half_as_ushort(__float2half(f));   // RTN
}
__device__ __forceinline__ float h2f(unsigned short h) {
  return __half2float(__ushort_as_half(h));
}
// relu on packed f16: sign bit = bit15, so int16 compare works (+0.0 = 0x0000)
__device__ __forceinline__ short8 relu8(short8 v) {
#pragma unroll
  for (int i = 0; i < 8; ++i) v[i] = (v[i] < (short)0) ? (short)0 : v[i];
  return v;
}

// ---------- bin indices for the 3 planes (+ fused count) ----------
__global__ __launch_bounds__(256) void k_idxcount(const float* __restrict__ p,
                                                  int* __restrict__ idx,
                                                  int* __restrict__ cnt) {
  int pt = blockIdx.x * 256 + threadIdx.x;
  const float DIVC = (float)(1.0 + 0.1 + 1e-5);
  const float HI = (float)(1.0 - 1e-5);
  float x = p[pt * 3 + 0], y = p[pt * 3 + 1], z = p[pt * 3 + 2];
  float nx = fminf(fmaxf(x / DIVC + 0.5f, 0.0f), HI);
  float ny = fminf(fmaxf(y / DIVC + 0.5f, 0.0f), HI);
  float nz = fminf(fmaxf(z / DIVC + 0.5f, 0.0f), HI);
  int ix = (int)(nx * (float)RESO_);
  int iy = (int)(ny * (float)RESO_);
  int iz = (int)(nz * (float)RESO_);
  int off = (pt >> 15) * R2_;
  int i0 = ix + RESO_ * iz + off;   // xz
  int i1 = ix + RESO_ * iy + off;   // xy
  int i2 = iy + RESO_ * iz + off;   // yz
  idx[0 * BTOT + pt] = i0;
  idx[1 * BTOT + pt] = i1;
  idx[2 * BTOT + pt] = i2;
  atomicAdd(&cnt[0 * NBIN + i0], 1);
  atomicAdd(&cnt[1 * NBIN + i1], 1);
  atomicAdd(&cnt[2 * NBIN + i2], 1);
}

__global__ __launch_bounds__(1024) void k_scan(const int* __restrict__ cnt,
                                               int* __restrict__ starts,
                                               int* __restrict__ cursor) {
  __shared__ int part[1024];
  int pl = blockIdx.x;
  int t = threadIdx.x;
  const int* c = cnt + pl * NBIN;
  int base = t * 64;
  int s = 0;
  for (int i = 0; i < 64; ++i) s += c[base + i];
  part[t] = s;
  __syncthreads();
  for (int off = 1; off < 1024; off <<= 1) {
    int v = (t >= off) ? part[t - off] : 0;
    __syncthreads();
    part[t] += v;
    __syncthreads();
  }
  int run = (t == 0) ? 0 : part[t - 1];
  int* st = starts + pl * (NBIN + 1);
  int* cur = cursor + pl * NBIN;
  for (int i = 0; i < 64; ++i) {
    st[base + i] = run;
    cur[base + i] = run;
    run += c[base + i];
  }
  if (t == 1023) st[NBIN] = run;
}

__global__ __launch_bounds__(256) void k_place(const int* __restrict__ idx,
                                               int* __restrict__ cursor,
                                               int* __restrict__ plist) {
  int e = blockIdx.x * 256 + threadIdx.x;    // 3*BTOT
  int pl = e / BTOT, pt = e - pl * BTOT;
  int pos = atomicAdd(&cursor[pl * NBIN + idx[e]], 1);
  plist[(size_t)pl * BTOT + pos] = pt;
}

// ---------- weight packing into MFMA B-fragment order (single f16) ----------
__global__ __launch_bounds__(256) void k_pack(const float* __restrict__ bw0,
                                              const float* __restrict__ bw1,
                                              const float* __restrict__ bws,
                                              unsigned short* __restrict__ P1,
                                              unsigned short* __restrict__ P2) {
  int t = blockIdx.x * 256 + threadIdx.x;
  if (t >= 5 * 20 * 8 * 64) return;
  int lane = t & 63;
  int r = t >> 6;
  int nt = r & 7; r >>= 3;
  int kb20 = r % 20;
  int l = r / 20;
  int quad = lane >> 4;
  int n = nt * 16 + (lane & 15);
#pragma unroll
  for (int j = 0; j < 8; ++j) {
    if (kb20 < 8) {
      int k = kb20 * 32 + quad * 8 + j;
      float v = bw0[((size_t)l * 256 + k) * 128 + n];
      size_t didx = (((size_t)(l * 8 + kb20) * 8 + nt) * 64 + lane) * 8 + j;
      P1[didx] = f2h(v);
    } else {
      int kb = kb20 - 8;
      int k = kb * 32 + quad * 8 + j;
      float v = (k < 256) ? bws[((size_t)l * 256 + k) * 128 + n]
                          : bw1[((size_t)l * 128 + (k - 256)) * 128 + n];
      size_t didx = (((size_t)(l * 12 + kb) * 8 + nt) * 64 + lane) * 8 + j;
      P2[didx] = f2h(v);
    }
  }
}

// ---------- fc_c weight packing: P3[(kb*4+nt)*64+lane][j] ----------
__global__ __launch_bounds__(256) void k_packc(const float* __restrict__ fccw,
                                               unsigned short* __restrict__ P3) {
  int t = blockIdx.x * 256 + threadIdx.x;    // 16 frags x 64 lanes
  if (t >= 16 * 64) return;
  int lane = t & 63;
  int fr = t >> 6;
  int nt = fr & 3, kb = fr >> 2;
  int quad = lane >> 4;
  int n = nt * 16 + (lane & 15);
#pragma unroll
  for (int j = 0; j < 8; ++j) {
    int k = kb * 32 + quad * 8 + j;
    P3[((size_t)fr * 64 + lane) * 8 + j] = f2h(fccw[(size_t)k * 64 + n]);
  }
}

// ---------- list-based pooling max (packed f16 max), 8 bins/wave ----------
// grid (NBIN/32, 3); block 256 = 4 waves x 8 bins. Lane covers 2 channels.
// 8 interleaved chains: double the outstanding loads vs 4 (latency-bound
// random HBM gathers ~900cyc); +~15% redundant masked iterations.
__global__ __launch_bounds__(256) void k_poolmax(const unsigned short* __restrict__ net,
                                                 const int* __restrict__ starts,
                                                 const int* __restrict__ plist,
                                                 unsigned short* __restrict__ seg) {
  int tid = threadIdx.x;
  int pl = blockIdx.y;
  int wv = tid >> 6, lane = tid & 63;
  int bin0 = blockIdx.x * 32 + wv * 8;
  const int* st = starts + pl * (NBIN + 1) + bin0;
  int sa[9];
#pragma unroll
  for (int i = 0; i < 9; ++i) sa[i] = st[i];
  const int* pli = plist + (size_t)pl * BTOT;
  half2v v[8];
#pragma unroll
  for (int i = 0; i < 8; ++i) {
    v[i][0] = (_Float16)(-65504.0f);
    v[i][1] = (_Float16)(-65504.0f);
  }
  int lmax = 0;
#pragma unroll
  for (int i = 0; i < 8; ++i) lmax = max(lmax, sa[i + 1] - sa[i]);
  for (int k = 0; k < lmax; ++k) {
#pragma unroll
    for (int i = 0; i < 8; ++i) {         // 8 independent load chains in flight
      int t = sa[i] + k;
      int kk = max(min(t, sa[i + 1] - 1), 0);
      int pid = pli[kk];
      unsigned u = *(const unsigned*)(net + (size_t)pid * 128 + lane * 2);
      half2v h = *(half2v*)&u;
      if (t < sa[i + 1]) v[i] = __builtin_elementwise_max(v[i], h);  // v_pk_max_f16
    }
  }
#pragma unroll
  for (int i = 0; i < 8; ++i) {
    if (sa[i + 1] > sa[i]) {               // empty bins never gathered
      *(unsigned*)(seg + ((size_t)pl * NBIN + bin0 + i) * 128 + lane * 2) =
          *(unsigned*)&v[i];
    }
  }
}

// ---------- fused resblock with in-kernel 3-plane gather (all f16) ----------
// 32 rows/block, 4 waves = col quarters; each wave 32 rows x 32 cols.
// 32r is the measured sweet spot (16r=71us / 32r=51us / 64r=56us).
// launch_bounds(256,4): measured residency is ~4 blocks/CU anyway (50% occ at
// (256,6)); cap 128 VGPRs so the scheduler can keep more loads in flight
// (round-2 binary had only 40 VGPRs -> serialized load->use chains).
// mode 2: fc_pos fused (x computed from p directly; netA/poolB round-trip and
// the separate fcpos dispatch eliminated).
// If cOut != nullptr: additionally computes c = net @ fc_c + bc (fused fc_c).
__global__ __launch_bounds__(256, 4) void k_resblock(
    const float* __restrict__ p, const float* __restrict__ fcw,
    const float* __restrict__ fcb,
    unsigned short* __restrict__ netA, const unsigned short* __restrict__ segB,
    const int* __restrict__ idx, int mode,
    const unsigned short* __restrict__ P1, const unsigned short* __restrict__ P2,
    const float* __restrict__ b0, const float* __restrict__ b1,
    const unsigned short* __restrict__ P3, const float* __restrict__ bc,
    unsigned short* __restrict__ cOut) {
  __shared__ __align__(16) unsigned short xh[32][264];
  __shared__ __align__(16) unsigned short th[32][136];
  __shared__ float pp[96];
  int tid = threadIdx.x;
  int rows0 = blockIdx.x * 32;

  if (mode == 2) {
    // fused fc_pos: x[row][0..256) = p[row] @ fcw + fcb, f16 RTN (identical
    // numerics to the old fcpos kernel: f32 accum -> f2h).
    if (tid < 96) pp[tid] = p[(size_t)rows0 * 3 + tid];
    __syncthreads();
    int g = (tid & 31) * 8;              // col group of 8
    int rh = tid >> 5;                   // row chunk [0,8) -> 4 rows each
    float wv0[8], wv1[8], wv2[8], bv[8];
#pragma unroll
    for (int j = 0; j < 8; ++j) {
      wv0[j] = fcw[g + j];
      wv1[j] = fcw[256 + g + j];
      wv2[j] = fcw[512 + g + j];
      bv[j] = fcb[g + j];
    }
#pragma unroll
    for (int rr = 0; rr < 4; ++rr) {
      int row = rh * 4 + rr;
      float x0 = pp[row * 3 + 0], x1 = pp[row * 3 + 1], x2 = pp[row * 3 + 2];
      short8 o;
#pragma unroll
      for (int j = 0; j < 8; ++j)
        o[j] = (short)f2h(bv[j] + x0 * wv0[j] + x1 * wv1[j] + x2 * wv2[j]);
      *(short8*)&xh[row][g] = o;
    }
  } else {
    // stage A: x = [netA | pooled] f16, 8-col groups
#pragma unroll
    for (int i = 0; i < 4; ++i) {
      int g8 = i * 256 + tid;             // [0,1024): 32 rows x 32 groups
      int row = g8 >> 5;
      int col = (g8 & 31) * 8;
      int grow = rows0 + row;
      if (col < 128) {
        *(short8*)&xh[row][col] = *(const short8*)(netA + (size_t)grow * 128 + col);
      } else {
        int cc = col - 128;
        int i0 = idx[grow], i1 = idx[BTOT + grow], i2 = idx[2 * BTOT + grow];
        short8 a = *(const short8*)(segB + (size_t)i0 * 128 + cc);
        short8 b8 = *(const short8*)(segB + (size_t)NBIN * 128 + (size_t)i1 * 128 + cc);
        short8 c8 = *(const short8*)(segB + (size_t)2 * NBIN * 128 + (size_t)i2 * 128 + cc);
        half8 s = *(half8*)&a + *(half8*)&b8 + *(half8*)&c8;   // v_pk_add_f16 x8
        *(short8*)&xh[row][col] = *(short8*)&s;
      }
    }
  }
  __syncthreads();

  int lane = tid & 63;
  int cg = tid >> 6;               // col quarter [0,4)
  int quad = lane >> 4;
  int m0 = lane & 15;

  // ---- stage 1: t = relu(x) @ w0 + b0 ----
  floatx4 acc[2][2] = {};
  for (int kb = 0; kb < 8; ++kb) {
    short8 as0 = relu8(*(const short8*)&xh[m0][kb * 32 + quad * 8]);
    short8 as1 = relu8(*(const short8*)&xh[m0 + 16][kb * 32 + quad * 8]);
    half8 a0 = *(half8*)&as0;
    half8 a1 = *(half8*)&as1;
    const short8* wf = (const short8*)P1 + ((size_t)(kb * 8 + cg * 2) * 64 + lane);
#pragma unroll
    for (int nti = 0; nti < 2; ++nti) {
      short8 bs = wf[nti * 64];
      half8 bw = *(half8*)&bs;
      acc[0][nti] = __builtin_amdgcn_mfma_f32_16x16x32_f16(a0, bw, acc[0][nti], 0, 0, 0);
      acc[1][nti] = __builtin_amdgcn_mfma_f32_16x16x32_f16(a1, bw, acc[1][nti], 0, 0, 0);
    }
  }
  // epilogue 1: bias + relu -> th (f16)
#pragma unroll
  for (int rs = 0; rs < 2; ++rs) {
#pragma unroll
    for (int nti = 0; nti < 2; ++nti) {
      int col = cg * 32 + nti * 16 + m0;
      float bb = b0[col];
#pragma unroll
      for (int r = 0; r < 4; ++r) {
        int row = rs * 16 + quad * 4 + r;
        th[row][col] = f2h(fmaxf(acc[rs][nti][r] + bb, 0.0f));
      }
    }
  }
  __syncthreads();

  // ---- stage 2: out = x @ ws + relu_t @ w1 + b1 ----
  floatx4 acc2[2][2] = {};
  for (int kb = 0; kb < 12; ++kb) {
    short8 as0, as1;
    if (kb < 8) {
      as0 = *(const short8*)&xh[m0][kb * 32 + quad * 8];
      as1 = *(const short8*)&xh[m0 + 16][kb * 32 + quad * 8];
    } else {
      as0 = *(const short8*)&th[m0][(kb - 8) * 32 + quad * 8];
      as1 = *(const short8*)&th[m0 + 16][(kb - 8) * 32 + quad * 8];
    }
    half8 a0 = *(half8*)&as0;
    half8 a1 = *(half8*)&as1;
    const short8* wf = (const short8*)P2 + ((size_t)(kb * 8 + cg * 2) * 64 + lane);
#pragma unroll
    for (int nti = 0; nti < 2; ++nti) {
      short8 bs = wf[nti * 64];
      half8 bw = *(half8*)&bs;
      acc2[0][nti] = __builtin_amdgcn_mfma_f32_16x16x32_f16(a0, bw, acc2[0][nti], 0, 0, 0);
      acc2[1][nti] = __builtin_amdgcn_mfma_f32_16x16x32_f16(a1, bw, acc2[1][nti], 0, 0, 0);
    }
  }

  if (!cOut) {
    // epilogue 2: bias + f16 store (in-place; block owns rows)
#pragma unroll
    for (int rs = 0; rs < 2; ++rs) {
#pragma unroll
      for (int nti = 0; nti < 2; ++nti) {
        int col = cg * 32 + nti * 16 + m0;
        float bb = b1[col];
#pragma unroll
        for (int r = 0; r < 4; ++r) {
          int row = rows0 + rs * 16 + quad * 4 + r;
          netA[(size_t)row * 128 + col] = f2h(acc2[rs][nti][r] + bb);
        }
      }
    }
  } else {
    // fused fc_c: round-trip net through xh, then 8 MFMAs per wave
    __syncthreads();                     // all waves done reading xh/th
#pragma unroll
    for (int rs = 0; rs < 2; ++rs) {
#pragma unroll
      for (int nti = 0; nti < 2; ++nti) {
        int col = cg * 32 + nti * 16 + m0;
        float bb = b1[col];
#pragma unroll
        for (int r = 0; r < 4; ++r) {
          int row = rs * 16 + quad * 4 + r;
          xh[row][col] = f2h(acc2[rs][nti][r] + bb);
        }
      }
    }
    __syncthreads();
    floatx4 acc3[2] = {};
    for (int kb = 0; kb < 4; ++kb) {
      short8 as0 = *(const short8*)&xh[m0][kb * 32 + quad * 8];
      short8 as1 = *(const short8*)&xh[m0 + 16][kb * 32 + quad * 8];
      short8 bs = *((const short8*)P3 + ((size_t)(kb * 4 + cg) * 64 + lane));
      half8 bw = *(half8*)&bs;
      acc3[0] = __builtin_amdgcn_mfma_f32_16x16x32_f16(*(half8*)&as0, bw, acc3[0], 0, 0, 0);
      acc3[1] = __builtin_amdgcn_mfma_f32_16x16x32_f16(*(half8*)&as1, bw, acc3[1], 0, 0, 0);
    }
    int col = cg * 16 + m0;
    float bb = bc[col];
#pragma unroll
    for (int rs = 0; rs < 2; ++rs) {
#pragma unroll
      for (int r = 0; r < 4; ++r) {
        int row = rows0 + rs * 16 + quad * 4 + r;
        cOut[(size_t)row * 64 + col] = f2h(acc3[rs][r] + bb);
      }
    }
  }
}

// ---------- fused list-based scatter-mean + transposed output ----------
// 4 bins per wave interleaved for load ILP.
__global__ __launch_bounds__(256) void k_meanout(const unsigned short* __restrict__ c,
                                                 const int* __restrict__ starts,
                                                 const int* __restrict__ plist,
                                                 float* __restrict__ out) {
  __shared__ float tile[64][65];
  int tid = threadIdx.x;
  int pb = blockIdx.y;                 // pl*4 + b
  int pl = pb >> 2;
  int b = pb & 3;
  int bin0 = blockIdx.x * 64;
  int w = tid >> 6, lane = tid & 63;
  const int* st = starts + pl * (NBIN + 1) + b * R2_ + bin0 + w * 16;
  const int* pli = plist + (size_t)pl * BTOT;
  for (int grp = 0; grp < 4; ++grp) {
    int sa[5];
#pragma unroll
    for (int i = 0; i < 5; ++i) sa[i] = st[grp * 4 + i];
    float sum[4] = {0.f, 0.f, 0.f, 0.f};
    int lmax = 0;
#pragma unroll
    for (int i = 0; i < 4; ++i) lmax = max(lmax, sa[i + 1] - sa[i]);
    for (int k = 0; k < lmax; ++k) {
#pragma unroll
      for (int i = 0; i < 4; ++i) {
        int t = sa[i] + k;
        int kk = max(min(t, sa[i + 1] - 1), 0);
        int pid = pli[kk];
        float v = h2f(c[(size_t)pid * 64 + lane]);
        if (t < sa[i + 1]) sum[i] += v;
      }
    }
#pragma unroll
    for (int i = 0; i < 4; ++i) {
      int lb = w * 16 + grp * 4 + i;
      tile[lb][lane] = sum[i] / fmaxf((float)(sa[i + 1] - sa[i]), 1.0f);
    }
  }
  __syncthreads();
#pragma unroll
  for (int i = 0; i < 16; ++i) {
    int e2 = i * 256 + tid;
    int ch = e2 >> 6, lb = e2 & 63;
    out[((size_t)pb * 64 + ch) * R2_ + bin0 + lb] = tile[lb][ch];
  }
}

extern "C" void kernel_launch(void* const* d_in, const int* in_sizes, int n_in,
                              void* d_out, int out_size, void* d_ws, size_t ws_size,
                              hipStream_t stream) {
  const float* p    = (const float*)d_in[0];
  const float* fcw  = (const float*)d_in[1];
  const float* fcb  = (const float*)d_in[2];
  const float* bw0  = (const float*)d_in[3];
  const float* bb0  = (const float*)d_in[4];
  const float* bw1  = (const float*)d_in[5];
  const float* bb1  = (const float*)d_in[6];
  const float* bws  = (const float*)d_in[7];
  const float* fccw = (const float*)d_in[8];
  const float* fccb = (const float*)d_in[9];
  float* out = (float*)d_out;

  char* ws = (char*)d_ws;
  const size_t P1_LAYER = 8 * 8 * 64 * 8;               // shorts
  const size_t P2_LAYER = 12 * 8 * 64 * 8;              // shorts

  size_t off = 0;
  unsigned short* netA = (unsigned short*)(ws + off); off += (size_t)BTOT * 128 * 2;
  unsigned short* cbuf = (unsigned short*)(ws + off); off += (size_t)BTOT * 64 * 2;
  int*   idx  = (int*)(ws + off);   off += (size_t)3 * BTOT * 4;
  unsigned short* P1 = (unsigned short*)(ws + off); off += 5 * P1_LAYER * 2;
  unsigned short* P2 = (unsigned short*)(ws + off); off += 5 * P2_LAYER * 2;
  unsigned short* P3 = (unsigned short*)(ws + off); off += (size_t)16 * 64 * 8 * 2;
  int* cntb   = (int*)(ws + off); off += (size_t)3 * NBIN * 4;
  int* starts = (int*)(ws + off); off += (size_t)3 * (NBIN + 1) * 4;
  int* cursor = (int*)(ws + off); off += (size_t)3 * NBIN * 4;
  int* plist  = (int*)(ws + off); off += (size_t)3 * BTOT * 4;
  off = (off + 255) & ~(size_t)255;
  unsigned short* seg = (unsigned short*)(ws + off); // 3*NBIN*128*2 = 50.3 MiB

  hipMemsetAsync(cntb, 0, (size_t)3 * NBIN * 4, stream);
  k_idxcount<<<BTOT / 256, 256, 0, stream>>>(p, idx, cntb);
  k_scan<<<3, 1024, 0, stream>>>(cntb, starts, cursor);
  k_place<<<3 * BTOT / 256, 256, 0, stream>>>(idx, cursor, plist);
  k_pack<<<200, 256, 0, stream>>>(bw0, bw1, bws, P1, P2);
  k_packc<<<4, 256, 0, stream>>>(fccw, P3);

  for (int blk = 0; blk < 5; ++blk) {
    if (blk > 0) {
      dim3 g(NBIN / 32, 3);
      k_poolmax<<<g, 256, 0, stream>>>(netA, starts, plist, seg);
    }
    k_resblock<<<BTOT / 32, 256, 0, stream>>>(
        p, fcw, fcb,
        netA, seg, idx, (blk == 0) ? 2 : 1,
        P1 + (size_t)blk * P1_LAYER, P2 + (size_t)blk * P2_LAYER,
        bb0 + (size_t)blk * 128, bb1 + (size_t)blk * 128,
        P3, fccb, (blk == 4) ? cbuf : (unsigned short*)nullptr);
  }

  dim3 gm(R2_ / 64, 12);
  k_meanout<<<gm, 256, 0, stream>>>(cbuf, starts, plist, out);
}

// Round 5
// 509.438 us; speedup vs baseline: 1.3012x; 1.2048x over previous
//
#include <hip/hip_runtime.h>
#include <hip/hip_fp16.h>
#include <cstddef>

static constexpr int BTOT = 131072;     // B*T
static constexpr int RESO_ = 128;
static constexpr int R2_ = RESO_ * RESO_;   // 16384
static constexpr int NBIN = 4 * R2_;        // B*R2 = 65536
static constexpr int HDIM = 128;
static constexpr int CDIM = 64;

typedef __attribute__((ext_vector_type(8))) short short8;
typedef _Float16 half8 __attribute__((ext_vector_type(8)));
typedef _Float16 half2v __attribute__((ext_vector_type(2)));
typedef __attribute__((ext_vector_type(4))) float floatx4;

__device__ __forceinline__ unsigned short f2h(float f) {
  return __half_as_ushort(__float2half(f));   // RTN
}
__device__ __forceinline__ float h2f(unsigned short h) {
  return __half2float(__ushort_as_half(h));
}
// relu on packed f16: sign bit = bit15, so int16 compare works (+0.0 = 0x0000)
__device__ __forceinline__ short8 relu8(short8 v) {
#pragma unroll
  for (int i = 0; i < 8; ++i) v[i] = (v[i] < (short)0) ? (short)0 : v[i];
  return v;
}

// ---------- bin indices for the 3 planes (+ fused count) ----------
__global__ __launch_bounds__(256) void k_idxcount(const float* __restrict__ p,
                                                  int* __restrict__ idx,
                                                  int* __restrict__ cnt) {
  int pt = blockIdx.x * 256 + threadIdx.x;
  const float DIVC = (float)(1.0 + 0.1 + 1e-5);
  const float HI = (float)(1.0 - 1e-5);
  float x = p[pt * 3 + 0], y = p[pt * 3 + 1], z = p[pt * 3 + 2];
  float nx = fminf(fmaxf(x / DIVC + 0.5f, 0.0f), HI);
  float ny = fminf(fmaxf(y / DIVC + 0.5f, 0.0f), HI);
  float nz = fminf(fmaxf(z / DIVC + 0.5f, 0.0f), HI);
  int ix = (int)(nx * (float)RESO_);
  int iy = (int)(ny * (float)RESO_);
  int iz = (int)(nz * (float)RESO_);
  int off = (pt >> 15) * R2_;
  int i0 = ix + RESO_ * iz + off;   // xz
  int i1 = ix + RESO_ * iy + off;   // xy
  int i2 = iy + RESO_ * iz + off;   // yz
  idx[0 * BTOT + pt] = i0;
  idx[1 * BTOT + pt] = i1;
  idx[2 * BTOT + pt] = i2;
  atomicAdd(&cnt[0 * NBIN + i0], 1);
  atomicAdd(&cnt[1 * NBIN + i1], 1);
  atomicAdd(&cnt[2 * NBIN + i2], 1);
}

__global__ __launch_bounds__(1024) void k_scan(const int* __restrict__ cnt,
                                               int* __restrict__ starts,
                                               int* __restrict__ cursor) {
  __shared__ int part[1024];
  int pl = blockIdx.x;
  int t = threadIdx.x;
  const int* c = cnt + pl * NBIN;
  int base = t * 64;
  int s = 0;
  for (int i = 0; i < 64; ++i) s += c[base + i];
  part[t] = s;
  __syncthreads();
  for (int off = 1; off < 1024; off <<= 1) {
    int v = (t >= off) ? part[t - off] : 0;
    __syncthreads();
    part[t] += v;
    __syncthreads();
  }
  int run = (t == 0) ? 0 : part[t - 1];
  int* st = starts + pl * (NBIN + 1);
  int* cur = cursor + pl * NBIN;
  for (int i = 0; i < 64; ++i) {
    st[base + i] = run;
    cur[base + i] = run;
    run += c[base + i];
  }
  if (t == 1023) st[NBIN] = run;
}

__global__ __launch_bounds__(256) void k_place(const int* __restrict__ idx,
                                               int* __restrict__ cursor,
                                               int* __restrict__ plist) {
  int e = blockIdx.x * 256 + threadIdx.x;    // 3*BTOT
  int pl = e / BTOT, pt = e - pl * BTOT;
  int pos = atomicAdd(&cursor[pl * NBIN + idx[e]], 1);
  plist[(size_t)pl * BTOT + pos] = pt;
}

// ---------- weight packing into MFMA B-fragment order (single f16) ----------
__global__ __launch_bounds__(256) void k_pack(const float* __restrict__ bw0,
                                              const float* __restrict__ bw1,
                                              const float* __restrict__ bws,
                                              unsigned short* __restrict__ P1,
                                              unsigned short* __restrict__ P2) {
  int t = blockIdx.x * 256 + threadIdx.x;
  if (t >= 5 * 20 * 8 * 64) return;
  int lane = t & 63;
  int r = t >> 6;
  int nt = r & 7; r >>= 3;
  int kb20 = r % 20;
  int l = r / 20;
  int quad = lane >> 4;
  int n = nt * 16 + (lane & 15);
#pragma unroll
  for (int j = 0; j < 8; ++j) {
    if (kb20 < 8) {
      int k = kb20 * 32 + quad * 8 + j;
      float v = bw0[((size_t)l * 256 + k) * 128 + n];
      size_t didx = (((size_t)(l * 8 + kb20) * 8 + nt) * 64 + lane) * 8 + j;
      P1[didx] = f2h(v);
    } else {
      int kb = kb20 - 8;
      int k = kb * 32 + quad * 8 + j;
      float v = (k < 256) ? bws[((size_t)l * 256 + k) * 128 + n]
                          : bw1[((size_t)l * 128 + (k - 256)) * 128 + n];
      size_t didx = (((size_t)(l * 12 + kb) * 8 + nt) * 64 + lane) * 8 + j;
      P2[didx] = f2h(v);
    }
  }
}

// ---------- fc_c weight packing: P3[(kb*4+nt)*64+lane][j] ----------
__global__ __launch_bounds__(256) void k_packc(const float* __restrict__ fccw,
                                               unsigned short* __restrict__ P3) {
  int t = blockIdx.x * 256 + threadIdx.x;    // 16 frags x 64 lanes
  if (t >= 16 * 64) return;
  int lane = t & 63;
  int fr = t >> 6;
  int nt = fr & 3, kb = fr >> 2;
  int quad = lane >> 4;
  int n = nt * 16 + (lane & 15);
#pragma unroll
  for (int j = 0; j < 8; ++j) {
    int k = kb * 32 + quad * 8 + j;
    P3[((size_t)fr * 64 + lane) * 8 + j] = f2h(fccw[(size_t)k * 64 + n]);
  }
}

// ---------- list-based pooling max (packed f16 max), 8 bins/wave ----------
// grid (NBIN/32, 3); block 256 = 4 waves x 8 bins. Lane covers 2 channels.
// Software-pipelined: pli[k+1] loads issue while the 8 net loads for k are
// in flight (random ~900cyc HBM gathers; overlap the two latency hops).
__global__ __launch_bounds__(256) void k_poolmax(const unsigned short* __restrict__ net,
                                                 const int* __restrict__ starts,
                                                 const int* __restrict__ plist,
                                                 unsigned short* __restrict__ seg) {
  int tid = threadIdx.x;
  int pl = blockIdx.y;
  int wv = tid >> 6, lane = tid & 63;
  int bin0 = blockIdx.x * 32 + wv * 8;
  const int* st = starts + pl * (NBIN + 1) + bin0;
  int sa[9];
#pragma unroll
  for (int i = 0; i < 9; ++i) sa[i] = st[i];
  const int* pli = plist + (size_t)pl * BTOT;
  half2v v[8];
#pragma unroll
  for (int i = 0; i < 8; ++i) {
    v[i][0] = (_Float16)(-65504.0f);
    v[i][1] = (_Float16)(-65504.0f);
  }
  int lmax = 0;
#pragma unroll
  for (int i = 0; i < 8; ++i) lmax = max(lmax, sa[i + 1] - sa[i]);
  int pid[8];
#pragma unroll
  for (int i = 0; i < 8; ++i) {
    int kk = max(min(sa[i], sa[i + 1] - 1), 0);
    pid[i] = pli[kk];
  }
  for (int k = 0; k < lmax; ++k) {
    unsigned u[8];
#pragma unroll
    for (int i = 0; i < 8; ++i)
      u[i] = *(const unsigned*)(net + (size_t)pid[i] * 128 + lane * 2);
    if (k + 1 < lmax) {
#pragma unroll
      for (int i = 0; i < 8; ++i) {
        int t = sa[i] + k + 1;
        int kk = max(min(t, sa[i + 1] - 1), 0);
        pid[i] = pli[kk];
      }
    }
#pragma unroll
    for (int i = 0; i < 8; ++i) {
      if (sa[i] + k < sa[i + 1]) {
        half2v h = *(half2v*)&u[i];
        v[i] = __builtin_elementwise_max(v[i], h);  // v_pk_max_f16
      }
    }
  }
#pragma unroll
  for (int i = 0; i < 8; ++i) {
    if (sa[i + 1] > sa[i]) {               // empty bins never gathered
      *(unsigned*)(seg + ((size_t)pl * NBIN + bin0 + i) * 128 + lane * 2) =
          *(unsigned*)&v[i];
    }
  }
}

// ---------- fused resblock with in-kernel 3-plane gather (all f16) ----------
// 32 rows/block, 4 waves = col quarters; each wave 32 rows x 32 cols.
// Both MFMA loops fully unrolled with depth-2 weight prefetch and depth-1
// A-operand prefetch in NAMED registers (compile-time indices): round-4
// binary had 40 VGPRs -> one load in flight -> MfmaUtil 15%. This forces
// the ~200cyc L2 weight latency and ~120cyc LDS latency off the critical
// path. mode 2: fc_pos fused. cOut != nullptr: fused fc_c.
__global__ __launch_bounds__(256, 4) void k_resblock(
    const float* __restrict__ p, const float* __restrict__ fcw,
    const float* __restrict__ fcb,
    unsigned short* __restrict__ netA, const unsigned short* __restrict__ segB,
    const int* __restrict__ idx, int mode,
    const unsigned short* __restrict__ P1, const unsigned short* __restrict__ P2,
    const float* __restrict__ b0, const float* __restrict__ b1,
    const unsigned short* __restrict__ P3, const float* __restrict__ bc,
    unsigned short* __restrict__ cOut) {
  __shared__ __align__(16) unsigned short xh[32][264];
  __shared__ __align__(16) unsigned short th[32][136];
  __shared__ float pp[96];
  int tid = threadIdx.x;
  int rows0 = blockIdx.x * 32;

  if (mode == 2) {
    // fused fc_pos: x[row][0..256) = p[row] @ fcw + fcb, f16 RTN
    if (tid < 96) pp[tid] = p[(size_t)rows0 * 3 + tid];
    __syncthreads();
    int g = (tid & 31) * 8;              // col group of 8
    int rh = tid >> 5;                   // row chunk [0,8) -> 4 rows each
    float wv0[8], wv1[8], wv2[8], bv[8];
#pragma unroll
    for (int j = 0; j < 8; ++j) {
      wv0[j] = fcw[g + j];
      wv1[j] = fcw[256 + g + j];
      wv2[j] = fcw[512 + g + j];
      bv[j] = fcb[g + j];
    }
#pragma unroll
    for (int rr = 0; rr < 4; ++rr) {
      int row = rh * 4 + rr;
      float x0 = pp[row * 3 + 0], x1 = pp[row * 3 + 1], x2 = pp[row * 3 + 2];
      short8 o;
#pragma unroll
      for (int j = 0; j < 8; ++j)
        o[j] = (short)f2h(bv[j] + x0 * wv0[j] + x1 * wv1[j] + x2 * wv2[j]);
      *(short8*)&xh[row][g] = o;
    }
  } else {
    // stage A: col group is invariant over a thread's 4 row-iterations,
    // so split into pure-netA threads and pure-gather threads; gather
    // threads issue all 12 seg loads before any consume.
    int col = (tid & 31) * 8;
    int rbase = tid >> 5;                // rows rbase + {0,8,16,24}
    if (col < 128) {
#pragma unroll
      for (int i = 0; i < 4; ++i) {
        int row = rbase + i * 8;
        *(short8*)&xh[row][col] =
            *(const short8*)(netA + (size_t)(rows0 + row) * 128 + col);
      }
    } else {
      int cc = col - 128;
      int i0[4], i1[4], i2[4];
#pragma unroll
      for (int i = 0; i < 4; ++i) {
        int grow = rows0 + rbase + i * 8;
        i0[i] = idx[grow];
        i1[i] = idx[BTOT + grow];
        i2[i] = idx[2 * BTOT + grow];
      }
      short8 av[4], bv8[4], cv8[4];
#pragma unroll
      for (int i = 0; i < 4; ++i) {
        av[i] = *(const short8*)(segB + (size_t)i0[i] * 128 + cc);
        bv8[i] = *(const short8*)(segB + (size_t)NBIN * 128 + (size_t)i1[i] * 128 + cc);
        cv8[i] = *(const short8*)(segB + (size_t)2 * NBIN * 128 + (size_t)i2[i] * 128 + cc);
      }
#pragma unroll
      for (int i = 0; i < 4; ++i) {
        half8 s = *(half8*)&av[i] + *(half8*)&bv8[i] + *(half8*)&cv8[i];
        *(short8*)&xh[rbase + i * 8][col] = *(short8*)&s;
      }
    }
  }
  __syncthreads();

  int lane = tid & 63;
  int cg = tid >> 6;               // col quarter [0,4)
  int quad = lane >> 4;
  int m0 = lane & 15;

#define LD_P1(kb, nti) \
  (((const short8*)P1)[(size_t)(((kb) * 8 + cg * 2 + (nti)) * 64 + lane)])
#define LD_P2(kb, nti) \
  (((const short8*)P2)[(size_t)(((kb) * 8 + cg * 2 + (nti)) * 64 + lane)])
#define MFMA16(a, b, c) __builtin_amdgcn_mfma_f32_16x16x32_f16((a), (b), (c), 0, 0, 0)

  // ---- stage 1: t = relu(x) @ w0 + b0 (depth-2 W prefetch, depth-1 A) ----
  floatx4 acc[2][2] = {};
  {
    short8 cw0 = LD_P1(0, 0), cw1 = LD_P1(0, 1);
    short8 nw0 = LD_P1(1, 0), nw1 = LD_P1(1, 1);
    short8 cx0 = *(const short8*)&xh[m0][quad * 8];
    short8 cx1 = *(const short8*)&xh[m0 + 16][quad * 8];
#pragma unroll
    for (int kb = 0; kb < 8; ++kb) {
      short8 nnw0, nnw1, nx0, nx1;
      if (kb + 2 < 8) { nnw0 = LD_P1(kb + 2, 0); nnw1 = LD_P1(kb + 2, 1); }
      if (kb + 1 < 8) {
        nx0 = *(const short8*)&xh[m0][(kb + 1) * 32 + quad * 8];
        nx1 = *(const short8*)&xh[m0 + 16][(kb + 1) * 32 + quad * 8];
      }
      short8 as0 = relu8(cx0), as1 = relu8(cx1);
      half8 a0 = *(half8*)&as0, a1 = *(half8*)&as1;
      half8 b0v = *(half8*)&cw0, b1v = *(half8*)&cw1;
      acc[0][0] = MFMA16(a0, b0v, acc[0][0]);
      acc[1][0] = MFMA16(a1, b0v, acc[1][0]);
      acc[0][1] = MFMA16(a0, b1v, acc[0][1]);
      acc[1][1] = MFMA16(a1, b1v, acc[1][1]);
      cw0 = nw0; cw1 = nw1; nw0 = nnw0; nw1 = nnw1;
      cx0 = nx0; cx1 = nx1;
    }
  }
  // epilogue 1: bias + relu -> th (f16)
#pragma unroll
  for (int rs = 0; rs < 2; ++rs) {
#pragma unroll
    for (int nti = 0; nti < 2; ++nti) {
      int col = cg * 32 + nti * 16 + m0;
      float bb = b0[col];
#pragma unroll
      for (int r = 0; r < 4; ++r) {
        int row = rs * 16 + quad * 4 + r;
        th[row][col] = f2h(fmaxf(acc[rs][nti][r] + bb, 0.0f));
      }
    }
  }
  __syncthreads();

  // ---- stage 2: out = x @ ws + relu_t @ w1 + b1 ----
#define LD_A2(kb, off)                                              \
  ((kb) < 8 ? *(const short8*)&xh[m0 + (off)][(kb) * 32 + quad * 8] \
            : *(const short8*)&th[m0 + (off)][((kb) - 8) * 32 + quad * 8])
  floatx4 acc2[2][2] = {};
  {
    short8 cw0 = LD_P2(0, 0), cw1 = LD_P2(0, 1);
    short8 nw0 = LD_P2(1, 0), nw1 = LD_P2(1, 1);
    short8 cx0 = LD_A2(0, 0);
    short8 cx1 = LD_A2(0, 16);
#pragma unroll
    for (int kb = 0; kb < 12; ++kb) {
      short8 nnw0, nnw1, nx0, nx1;
      if (kb + 2 < 12) { nnw0 = LD_P2(kb + 2, 0); nnw1 = LD_P2(kb + 2, 1); }
      if (kb + 1 < 12) {
        nx0 = LD_A2(kb + 1, 0);
        nx1 = LD_A2(kb + 1, 16);
      }
      half8 a0 = *(half8*)&cx0, a1 = *(half8*)&cx1;
      half8 b0v = *(half8*)&cw0, b1v = *(half8*)&cw1;
      acc2[0][0] = MFMA16(a0, b0v, acc2[0][0]);
      acc2[1][0] = MFMA16(a1, b0v, acc2[1][0]);
      acc2[0][1] = MFMA16(a0, b1v, acc2[0][1]);
      acc2[1][1] = MFMA16(a1, b1v, acc2[1][1]);
      cw0 = nw0; cw1 = nw1; nw0 = nnw0; nw1 = nnw1;
      cx0 = nx0; cx1 = nx1;
    }
  }

  if (!cOut) {
    // epilogue 2: bias + f16 store (in-place; block owns rows)
#pragma unroll
    for (int rs = 0; rs < 2; ++rs) {
#pragma unroll
      for (int nti = 0; nti < 2; ++nti) {
        int col = cg * 32 + nti * 16 + m0;
        float bb = b1[col];
#pragma unroll
        for (int r = 0; r < 4; ++r) {
          int row = rows0 + rs * 16 + quad * 4 + r;
          netA[(size_t)row * 128 + col] = f2h(acc2[rs][nti][r] + bb);
        }
      }
    }
  } else {
    // fused fc_c: round-trip net through xh, then 8 MFMAs per wave
    __syncthreads();                     // all waves done reading xh/th
#pragma unroll
    for (int rs = 0; rs < 2; ++rs) {
#pragma unroll
      for (int nti = 0; nti < 2; ++nti) {
        int col = cg * 32 + nti * 16 + m0;
        float bb = b1[col];
#pragma unroll
        for (int r = 0; r < 4; ++r) {
          int row = rs * 16 + quad * 4 + r;
          xh[row][col] = f2h(acc2[rs][nti][r] + bb);
        }
      }
    }
    __syncthreads();
    floatx4 acc3[2] = {};
#pragma unroll
    for (int kb = 0; kb < 4; ++kb) {
      short8 as0 = *(const short8*)&xh[m0][kb * 32 + quad * 8];
      short8 as1 = *(const short8*)&xh[m0 + 16][kb * 32 + quad * 8];
      short8 bs = *((const short8*)P3 + ((size_t)(kb * 4 + cg) * 64 + lane));
      half8 bw = *(half8*)&bs;
      acc3[0] = MFMA16(*(half8*)&as0, bw, acc3[0]);
      acc3[1] = MFMA16(*(half8*)&as1, bw, acc3[1]);
    }
    int col = cg * 16 + m0;
    float bb = bc[col];
#pragma unroll
    for (int rs = 0; rs < 2; ++rs) {
#pragma unroll
      for (int r = 0; r < 4; ++r) {
        int row = rows0 + rs * 16 + quad * 4 + r;
        cOut[(size_t)row * 64 + col] = f2h(acc3[rs][r] + bb);
      }
    }
  }
#undef LD_P1
#undef LD_P2
#undef LD_A2
#undef MFMA16
}

// ---------- fused list-based scatter-mean + transposed output ----------
// 4 bins per wave interleaved; pid prefetched one iteration ahead.
__global__ __launch_bounds__(256) void k_meanout(const unsigned short* __restrict__ c,
                                                 const int* __restrict__ starts,
                                                 const int* __restrict__ plist,
                                                 float* __restrict__ out) {
  __shared__ float tile[64][65];
  int tid = threadIdx.x;
  int pb = blockIdx.y;                 // pl*4 + b
  int pl = pb >> 2;
  int b = pb & 3;
  int bin0 = blockIdx.x * 64;
  int w = tid >> 6, lane = tid & 63;
  const int* st = starts + pl * (NBIN + 1) + b * R2_ + bin0 + w * 16;
  const int* pli = plist + (size_t)pl * BTOT;
  for (int grp = 0; grp < 4; ++grp) {
    int sa[5];
#pragma unroll
    for (int i = 0; i < 5; ++i) sa[i] = st[grp * 4 + i];
    float sum[4] = {0.f, 0.f, 0.f, 0.f};
    int lmax = 0;
#pragma unroll
    for (int i = 0; i < 4; ++i) lmax = max(lmax, sa[i + 1] - sa[i]);
    int pid[4];
#pragma unroll
    for (int i = 0; i < 4; ++i) {
      int kk = max(min(sa[i], sa[i + 1] - 1), 0);
      pid[i] = pli[kk];
    }
    for (int k = 0; k < lmax; ++k) {
      unsigned short u[4];
#pragma unroll
      for (int i = 0; i < 4; ++i)
        u[i] = c[(size_t)pid[i] * 64 + lane];
      if (k + 1 < lmax) {
#pragma unroll
        for (int i = 0; i < 4; ++i) {
          int t = sa[i] + k + 1;
          int kk = max(min(t, sa[i + 1] - 1), 0);
          pid[i] = pli[kk];
        }
      }
#pragma unroll
      for (int i = 0; i < 4; ++i) {
        if (sa[i] + k < sa[i + 1]) sum[i] += h2f(u[i]);
      }
    }
#pragma unroll
    for (int i = 0; i < 4; ++i) {
      int lb = w * 16 + grp * 4 + i;
      tile[lb][lane] = sum[i] / fmaxf((float)(sa[i + 1] - sa[i]), 1.0f);
    }
  }
  __syncthreads();
#pragma unroll
  for (int i = 0; i < 16; ++i) {
    int e2 = i * 256 + tid;
    int ch = e2 >> 6, lb = e2 & 63;
    out[((size_t)pb * 64 + ch) * R2_ + bin0 + lb] = tile[lb][ch];
  }
}

extern "C" void kernel_launch(void* const* d_in, const int* in_sizes, int n_in,
                              void* d_out, int out_size, void* d_ws, size_t ws_size,
                              hipStream_t stream) {
  const float* p    = (const float*)d_in[0];
  const float* fcw  = (const float*)d_in[1];
  const float* fcb  = (const float*)d_in[2];
  const float* bw0  = (const float*)d_in[3];
  const float* bb0  = (const float*)d_in[4];
  const float* bw1  = (const float*)d_in[5];
  const float* bb1  = (const float*)d_in[6];
  const float* bws  = (const float*)d_in[7];
  const float* fccw = (const float*)d_in[8];
  const float* fccb = (const float*)d_in[9];
  float* out = (float*)d_out;

  char* ws = (char*)d_ws;
  const size_t P1_LAYER = 8 * 8 * 64 * 8;               // shorts
  const size_t P2_LAYER = 12 * 8 * 64 * 8;              // shorts

  size_t off = 0;
  unsigned short* netA = (unsigned short*)(ws + off); off += (size_t)BTOT * 128 * 2;
  unsigned short* cbuf = (unsigned short*)(ws + off); off += (size_t)BTOT * 64 * 2;
  int*   idx  = (int*)(ws + off);   off += (size_t)3 * BTOT * 4;
  unsigned short* P1 = (unsigned short*)(ws + off); off += 5 * P1_LAYER * 2;
  unsigned short* P2 = (unsigned short*)(ws + off); off += 5 * P2_LAYER * 2;
  unsigned short* P3 = (unsigned short*)(ws + off); off += (size_t)16 * 64 * 8 * 2;
  int* cntb   = (int*)(ws + off); off += (size_t)3 * NBIN * 4;
  int* starts = (int*)(ws + off); off += (size_t)3 * (NBIN + 1) * 4;
  int* cursor = (int*)(ws + off); off += (size_t)3 * NBIN * 4;
  int* plist  = (int*)(ws + off); off += (size_t)3 * BTOT * 4;
  off = (off + 255) & ~(size_t)255;
  unsigned short* seg = (unsigned short*)(ws + off); // 3*NBIN*128*2 = 50.3 MiB

  hipMemsetAsync(cntb, 0, (size_t)3 * NBIN * 4, stream);
  k_idxcount<<<BTOT / 256, 256, 0, stream>>>(p, idx, cntb);
  k_scan<<<3, 1024, 0, stream>>>(cntb, starts, cursor);
  k_place<<<3 * BTOT / 256, 256, 0, stream>>>(idx, cursor, plist);
  k_pack<<<200, 256, 0, stream>>>(bw0, bw1, bws, P1, P2);
  k_packc<<<4, 256, 0, stream>>>(fccw, P3);

  for (int blk = 0; blk < 5; ++blk) {
    if (blk > 0) {
      dim3 g(NBIN / 32, 3);
      k_poolmax<<<g, 256, 0, stream>>>(netA, starts, plist, seg);
    }
    k_resblock<<<BTOT / 32, 256, 0, stream>>>(
        p, fcw, fcb,
        netA, seg, idx, (blk == 0) ? 2 : 1,
        P1 + (size_t)blk * P1_LAYER, P2 + (size_t)blk * P2_LAYER,
        bb0 + (size_t)blk * 128, bb1 + (size_t)blk * 128,
        P3, fccb, (blk == 4) ? cbuf : (unsigned short*)nullptr);
  }

  dim3 gm(R2_ / 64, 12);
  k_meanout<<<gm, 256, 0, stream>>>(cbuf, starts, plist, out);
}